// Round 1
// baseline (58.622 us; speedup 1.0000x reference)
//
#include <hip/hip_runtime.h>

#define T_TXT 2048
#define TPB 1024
#define NWAVE (TPB / 64)

__global__ __launch_bounds__(TPB) void length_regulator_kernel(
    const float* __restrict__ dur,
    const int*   __restrict__ dur_padding,
    int*         __restrict__ out,
    int T_speech)
{
    __shared__ int c[T_TXT];       // per-row inclusive cumsum
    __shared__ int wsum[NWAVE];    // per-wave sums

    const int row  = blockIdx.x;
    const int tid  = threadIdx.x;
    const int lane = tid & 63;
    const int wid  = tid >> 6;

    const float* drow = dur         + (size_t)row * T_TXT;
    const int*   prow = dur_padding + (size_t)row * T_TXT;

    // ---- load 2 elements per thread, compute d = round(dur*ALPHA)*(1-pad) ----
    const int i0 = tid * 2;
    float f0 = drow[i0];
    float f1 = drow[i0 + 1];
    int   p0 = prow[i0];
    int   p1 = prow[i0 + 1];
    int d0 = (int)rintf(f0) * (1 - p0);   // ALPHA == 1.0
    int d1 = (int)rintf(f1) * (1 - p1);

    // thread-local inclusive partials
    int s0 = d0;
    int s1 = d0 + d1;

    // ---- wave-level inclusive scan of s1 (64 lanes) ----
    int incl = s1;
    #pragma unroll
    for (int off = 1; off < 64; off <<= 1) {
        int up = __shfl_up(incl, off, 64);
        if (lane >= off) incl += up;
    }
    int excl = incl - s1;                  // exclusive prefix within wave
    if (lane == 63) wsum[wid] = incl;      // wave total
    __syncthreads();

    // ---- cross-wave offsets + block total (16 values, read by all) ----
    int woff = 0, total = 0;
    #pragma unroll
    for (int w = 0; w < NWAVE; ++w) {
        int v = wsum[w];
        total += v;
        if (w < wid) woff += v;
    }

    const int base = woff + excl;
    c[i0]     = base + s0;
    c[i0 + 1] = base + s1;
    __syncthreads();

    // ---- scatter: token t covers output positions [c[t-1], c[t]) with value t+1 ----
    int* orow = out + (size_t)row * T_speech;
    #pragma unroll
    for (int it = 0; it < T_TXT / TPB; ++it) {
        const int t     = tid + it * TPB;
        const int start = (t == 0) ? 0 : c[t - 1];
        const int end   = c[t];
        const int val   = t + 1;
        for (int p = start; p < end; ++p) orow[p] = val;
    }

    // ---- zero-fill tail [total, T_speech) (d_out is poisoned before each launch) ----
    for (int p = total + tid; p < T_speech; p += TPB) orow[p] = 0;
}

extern "C" void kernel_launch(void* const* d_in, const int* in_sizes, int n_in,
                              void* d_out, int out_size, void* d_ws, size_t ws_size,
                              hipStream_t stream) {
    (void)n_in; (void)d_ws; (void)ws_size;
    const float* dur         = (const float*)d_in[0];
    const int*   dur_padding = (const int*)d_in[1];
    int*         out         = (int*)d_out;

    const int B        = in_sizes[0] / T_TXT;
    const int T_speech = out_size / B;

    length_regulator_kernel<<<B, TPB, 0, stream>>>(dur, dur_padding, out, T_speech);
}

// Round 2
// 56.116 us; speedup vs baseline: 1.0447x; 1.0447x over previous
//
#include <hip/hip_runtime.h>

#define T_TXT  2048
#define TPB    256
#define EPT    (T_TXT / TPB)     // 8 elements per thread
#define NWAVE  (TPB / 64)        // 4 waves
#define NSLICE 16                // scatter slices per row -> B*NSLICE = 256 blocks
#define TOK_PER_SLICE (T_TXT / NSLICE)  // 128 tokens per slice

__global__ __launch_bounds__(TPB) void length_regulator_kernel(
    const float* __restrict__ dur,
    const int*   __restrict__ dur_padding,
    int*         __restrict__ out,
    int T_speech)
{
    __shared__ int c[T_TXT];      // full-row inclusive cumsum (8 KB)
    __shared__ int wsum[NWAVE];

    const int row   = blockIdx.x;
    const int slice = blockIdx.y;
    const int tid   = threadIdx.x;
    const int lane  = tid & 63;
    const int wid   = tid >> 6;

    const float* drow = dur         + (size_t)row * T_TXT;
    const int*   prow = dur_padding + (size_t)row * T_TXT;

    // ---- vectorized load: 8 contiguous elements per thread (32B-aligned) ----
    const int i0 = tid * EPT;
    const float4 f0 = ((const float4*)(drow + i0))[0];
    const float4 f1 = ((const float4*)(drow + i0))[1];
    const int4   p0 = ((const int4*)(prow + i0))[0];
    const int4   p1 = ((const int4*)(prow + i0))[1];

    // d = round(dur*ALPHA) * (1-pad), ALPHA==1; local inclusive scan of 8
    int s[EPT];
    s[0] = (int)rintf(f0.x) * (1 - p0.x);
    s[1] = s[0] + (int)rintf(f0.y) * (1 - p0.y);
    s[2] = s[1] + (int)rintf(f0.z) * (1 - p0.z);
    s[3] = s[2] + (int)rintf(f0.w) * (1 - p0.w);
    s[4] = s[3] + (int)rintf(f1.x) * (1 - p1.x);
    s[5] = s[4] + (int)rintf(f1.y) * (1 - p1.y);
    s[6] = s[5] + (int)rintf(f1.z) * (1 - p1.z);
    s[7] = s[6] + (int)rintf(f1.w) * (1 - p1.w);

    // ---- wave-level inclusive scan of per-thread totals ----
    int incl = s[EPT - 1];
    #pragma unroll
    for (int off = 1; off < 64; off <<= 1) {
        int up = __shfl_up(incl, off, 64);
        if (lane >= off) incl += up;
    }
    const int excl = incl - s[EPT - 1];   // exclusive prefix within wave
    if (lane == 63) wsum[wid] = incl;
    __syncthreads();

    // ---- cross-wave offsets + row total ----
    int woff = 0, total = 0;
    #pragma unroll
    for (int w = 0; w < NWAVE; ++w) {
        int v = wsum[w];
        total += v;
        if (w < wid) woff += v;
    }

    const int base = woff + excl;
    #pragma unroll
    for (int j = 0; j < EPT; ++j) c[i0 + j] = base + s[j];
    __syncthreads();

    // ---- scatter this block's 128-token slice ----
    int* orow = out + (size_t)row * T_speech;
    if (tid < TOK_PER_SLICE) {
        const int t     = slice * TOK_PER_SLICE + tid;
        const int start = (t == 0) ? 0 : c[t - 1];
        const int end   = c[t];
        const int val   = t + 1;
        for (int p = start; p < end; ++p) orow[p] = val;
    }

    // ---- zero-fill stripe of tail [total, T_speech) (d_out is poisoned) ----
    for (int p = total + slice * TPB + tid; p < T_speech; p += NSLICE * TPB)
        orow[p] = 0;
}

extern "C" void kernel_launch(void* const* d_in, const int* in_sizes, int n_in,
                              void* d_out, int out_size, void* d_ws, size_t ws_size,
                              hipStream_t stream) {
    (void)n_in; (void)d_ws; (void)ws_size;
    const float* dur         = (const float*)d_in[0];
    const int*   dur_padding = (const int*)d_in[1];
    int*         out         = (int*)d_out;

    const int B        = in_sizes[0] / T_TXT;
    const int T_speech = out_size / B;

    dim3 grid(B, NSLICE);
    length_regulator_kernel<<<grid, TPB, 0, stream>>>(dur, dur_padding, out, T_speech);
}